// Round 1
// baseline (177.457 us; speedup 1.0000x reference)
//
#include <hip/hip_runtime.h>
#include <hip/hip_bf16.h>
#include <stdint.h>

#define N_ROWS 8192
#define DIM    768
#define BM     128
#define BN     128
#define BK     64
#define KTILES (DIM / BK)     // 12
#define NTILES (N_ROWS / BN)  // 64

typedef __attribute__((ext_vector_type(8))) short bf16x8;
typedef __attribute__((ext_vector_type(4))) float f32x4;

__device__ __forceinline__ float bf2f(unsigned short u) {
    union { uint32_t i; float f; } v; v.i = ((uint32_t)u) << 16; return v.f;
}
__device__ __forceinline__ unsigned short f2bf(float f) {
    union { float f; uint32_t i; } v; v.f = f;
    uint32_t u = v.i;
    return (unsigned short)((u + 0x7FFFu + ((u >> 16) & 1u)) >> 16);
}
__device__ __forceinline__ float tstudent(float c) {
    // (1 + 0.5*(1-c))^{-1.5} = t^{-1.5}, t = 1.5 - 0.5c
    float t = 1.5f - 0.5f * c;
    float r = rsqrtf(t);
    return r * r * r;
}

// ---------------- kernel 1: row L2-normalize fp32 -> bf16 ----------------
__global__ __launch_bounds__(256) void norm_kernel(const float* __restrict__ z1,
                                                   const float* __restrict__ z2,
                                                   unsigned short* __restrict__ n1,
                                                   unsigned short* __restrict__ n2) {
    int row = blockIdx.x;
    const float* src;
    unsigned short* dst;
    if (row < N_ROWS) { src = z1 + (size_t)row * DIM; dst = n1 + (size_t)row * DIM; }
    else              { src = z2 + (size_t)(row - N_ROWS) * DIM; dst = n2 + (size_t)(row - N_ROWS) * DIM; }
    int t = threadIdx.x;
    float x0 = src[t], x1 = src[t + 256], x2 = src[t + 512];
    float ss = x0 * x0 + x1 * x1 + x2 * x2;
    for (int off = 32; off; off >>= 1) ss += __shfl_down(ss, off);
    __shared__ float wsum[4];
    __shared__ float scale_s;
    if ((t & 63) == 0) wsum[t >> 6] = ss;
    __syncthreads();
    if (t == 0) {
        float nrm = sqrtf(wsum[0] + wsum[1] + wsum[2] + wsum[3]);
        nrm = fmaxf(nrm, 1e-8f);
        scale_s = 1.0f / nrm;
    }
    __syncthreads();
    float sc = scale_s;
    dst[t]       = f2bf(x0 * sc);
    dst[t + 256] = f2bf(x1 * sc);
    dst[t + 512] = f2bf(x2 * sc);
}

// ---------------- kernel 2: numerator (diag) ----------------
__global__ __launch_bounds__(64) void num_kernel(const unsigned short* __restrict__ n1,
                                                 const unsigned short* __restrict__ n2,
                                                 float* __restrict__ num) {
    int row = blockIdx.x;
    int l = threadIdx.x;
    const unsigned short* a = n1 + (size_t)row * DIM;
    const unsigned short* b = n2 + (size_t)row * DIM;
    float d = 0.f;
    #pragma unroll
    for (int j = 0; j < DIM / 64; ++j) {
        d += bf2f(a[l + j * 64]) * bf2f(b[l + j * 64]);
    }
    for (int off = 32; off; off >>= 1) d += __shfl_down(d, off);
    if (l == 0) num[row] = tstudent(d);
}

// ---------------- kernel 3: MFMA GEMM + t-Student row partial sums ----------------
__global__ __launch_bounds__(256) void gemm_kernel(const unsigned short* __restrict__ n1,
                                                   const unsigned short* __restrict__ n2,
                                                   float* __restrict__ partial) {
    __shared__ __align__(16) short As[BM][BK];   // 16 KB
    __shared__ __align__(16) short Bs[BN][BK];   // 16 KB
    __shared__ float red[BM][2];                 // 1 KB

    int t = threadIdx.x;
    int bc = blockIdx.x, br = blockIdx.y;
    int rowbase = br * BM, colbase = bc * BN;

    f32x4 acc[4][4] = {};

    int l = t & 63;
    int w = t >> 6;
    int wr = w >> 1, wc = w & 1;

    // staging decomposition: thread t loads 16B: row (t>>3)+i*32, k seg (t&7)*8
    int srow = t >> 3;
    int sseg = (t & 7) * 8;
    const unsigned short* Ag = n1 + (size_t)(rowbase + srow) * DIM + sseg;
    const unsigned short* Bg = n2 + (size_t)(colbase + srow) * DIM + sseg;

    for (int kt = 0; kt < KTILES; ++kt) {
        int k0 = kt * BK;
        #pragma unroll
        for (int i = 0; i < 4; ++i) {
            // LDS dest: wave-uniform base + lane*16 == t*16 + i*4096 (linear layout)
            __builtin_amdgcn_global_load_lds(
                (__attribute__((address_space(1))) void*)(Ag + k0 + i * 32 * DIM),
                (__attribute__((address_space(3))) void*)((char*)&As[0][0] + i * 4096 + (t & 192) * 16),
                16, 0, 0);
            __builtin_amdgcn_global_load_lds(
                (__attribute__((address_space(1))) void*)(Bg + k0 + i * 32 * DIM),
                (__attribute__((address_space(3))) void*)((char*)&Bs[0][0] + i * 4096 + (t & 192) * 16),
                16, 0, 0);
        }
        __syncthreads();  // drains vmcnt before barrier (compiler-enforced)
        #pragma unroll
        for (int ks = 0; ks < BK; ks += 32) {
            bf16x8 af[4], bfr[4];
            int kf = ks + (l >> 4) * 8;
            #pragma unroll
            for (int m = 0; m < 4; ++m)
                af[m] = *(const bf16x8*)&As[wr * 64 + m * 16 + (l & 15)][kf];
            #pragma unroll
            for (int n = 0; n < 4; ++n)
                bfr[n] = *(const bf16x8*)&Bs[wc * 64 + n * 16 + (l & 15)][kf];
            #pragma unroll
            for (int m = 0; m < 4; ++m)
                #pragma unroll
                for (int n = 0; n < 4; ++n)
                    acc[m][n] = __builtin_amdgcn_mfma_f32_16x16x32_bf16(af[m], bfr[n], acc[m][n], 0, 0, 0);
        }
        __syncthreads();
    }

    // epilogue: t-Student + row sums.
    // C/D mapping (verified m89): row = A-side = m*16 + (l>>4)*4 + j, col = B-side = n*16 + (l&15)
    #pragma unroll
    for (int m = 0; m < 4; ++m) {
        #pragma unroll
        for (int j = 0; j < 4; ++j) {
            float s = 0.f;
            #pragma unroll
            for (int n = 0; n < 4; ++n) s += tstudent(acc[m][n][j]);
            s += __shfl_xor(s, 1);
            s += __shfl_xor(s, 2);
            s += __shfl_xor(s, 4);
            s += __shfl_xor(s, 8);
            if ((l & 15) == 0) red[wr * 64 + m * 16 + (l >> 4) * 4 + j][wc] = s;
        }
    }
    __syncthreads();
    if (t < BM) {
        partial[(size_t)bc * N_ROWS + rowbase + t] = red[t][0] + red[t][1];
    }
}

// ---------------- kernel 4: per-row denom + ratio, per-block sums ----------------
__global__ __launch_bounds__(256) void reduce_kernel(const float* __restrict__ partial,
                                                     const float* __restrict__ num,
                                                     float* __restrict__ blocksum) {
    int row = blockIdx.x * 256 + threadIdx.x;
    float d = 0.f;
    #pragma unroll 8
    for (int ct = 0; ct < NTILES; ++ct) d += partial[(size_t)ct * N_ROWS + row];
    float s = num[row] / d;
    for (int off = 32; off; off >>= 1) s += __shfl_down(s, off);
    __shared__ float wsum[4];
    if ((threadIdx.x & 63) == 0) wsum[threadIdx.x >> 6] = s;
    __syncthreads();
    if (threadIdx.x == 0) blocksum[blockIdx.x] = wsum[0] + wsum[1] + wsum[2] + wsum[3];
}

// ---------------- kernel 5: final scalar ----------------
__global__ __launch_bounds__(64) void final_kernel(const float* __restrict__ blocksum,
                                                   float* __restrict__ out) {
    int l = threadIdx.x;
    float s = (l < 32) ? blocksum[l] : 0.f;
    for (int off = 32; off; off >>= 1) s += __shfl_down(s, off);
    if (l == 0) out[0] = -(s / (float)N_ROWS);
}

extern "C" void kernel_launch(void* const* d_in, const int* in_sizes, int n_in,
                              void* d_out, int out_size, void* d_ws, size_t ws_size,
                              hipStream_t stream) {
    const float* z1 = (const float*)d_in[0];
    const float* z2 = (const float*)d_in[1];
    char* ws = (char*)d_ws;
    const size_t n_bytes = (size_t)N_ROWS * DIM * 2;  // 12,582,912
    unsigned short* n1 = (unsigned short*)ws;
    unsigned short* n2 = (unsigned short*)(ws + n_bytes);
    float* num      = (float*)(ws + 2 * n_bytes);                         // 32 KB
    float* partial  = (float*)(ws + 2 * n_bytes + 32768);                 // 2 MB
    float* blocksum = (float*)(ws + 2 * n_bytes + 32768 + 2097152);       // 128 B

    norm_kernel<<<2 * N_ROWS, 256, 0, stream>>>(z1, z2, n1, n2);
    num_kernel<<<N_ROWS, 64, 0, stream>>>(n1, n2, num);
    dim3 g(NTILES, NTILES);
    gemm_kernel<<<g, 256, 0, stream>>>(n1, n2, partial);
    reduce_kernel<<<N_ROWS / 256, 256, 0, stream>>>(partial, num, blocksum);
    final_kernel<<<1, 64, 0, stream>>>(blocksum, (float*)d_out);
}

// Round 2
// 140.926 us; speedup vs baseline: 1.2592x; 1.2592x over previous
//
#include <hip/hip_runtime.h>
#include <hip/hip_bf16.h>
#include <stdint.h>

#define N_ROWS 8192
#define DIM    768
#define BM     256
#define BN     256
#define BK     64
#define KTILES (DIM / BK)      // 12
#define NT2    (N_ROWS / BN)   // 32 col-tiles
#define LDS_BYTES 131072

typedef __attribute__((ext_vector_type(8))) short bf16x8;
typedef __attribute__((ext_vector_type(4))) float f32x4;

__device__ __forceinline__ float bf2f(unsigned short u) {
    union { uint32_t i; float f; } v; v.i = ((uint32_t)u) << 16; return v.f;
}
__device__ __forceinline__ unsigned short f2bf(float f) {
    union { float f; uint32_t i; } v; v.f = f;
    uint32_t u = v.i;
    return (unsigned short)((u + 0x7FFFu + ((u >> 16) & 1u)) >> 16);
}
__device__ __forceinline__ float tstudent(float c) {
    // (1 + 0.5*(1-c))^{-1.5} = t^{-1.5}, t = 1.5 - 0.5c
    float t = 1.5f - 0.5f * c;
    float r = rsqrtf(t);
    return r * r * r;
}

// ---------------- kernel 1: row L2-normalize fp32 -> bf16 ----------------
__global__ __launch_bounds__(256) void norm_kernel(const float* __restrict__ z1,
                                                   const float* __restrict__ z2,
                                                   unsigned short* __restrict__ n1,
                                                   unsigned short* __restrict__ n2) {
    int row = blockIdx.x;
    const float* src;
    unsigned short* dst;
    if (row < N_ROWS) { src = z1 + (size_t)row * DIM; dst = n1 + (size_t)row * DIM; }
    else              { src = z2 + (size_t)(row - N_ROWS) * DIM; dst = n2 + (size_t)(row - N_ROWS) * DIM; }
    int t = threadIdx.x;
    float x0 = src[t], x1 = src[t + 256], x2 = src[t + 512];
    float ss = x0 * x0 + x1 * x1 + x2 * x2;
    for (int off = 32; off; off >>= 1) ss += __shfl_down(ss, off);
    __shared__ float wsum[4];
    __shared__ float scale_s;
    if ((t & 63) == 0) wsum[t >> 6] = ss;
    __syncthreads();
    if (t == 0) {
        float nrm = sqrtf(wsum[0] + wsum[1] + wsum[2] + wsum[3]);
        nrm = fmaxf(nrm, 1e-8f);
        scale_s = 1.0f / nrm;
    }
    __syncthreads();
    float sc = scale_s;
    dst[t]       = f2bf(x0 * sc);
    dst[t + 256] = f2bf(x1 * sc);
    dst[t + 512] = f2bf(x2 * sc);
}

// ---------------- kernel 2: numerator (diag) ----------------
__global__ __launch_bounds__(64) void num_kernel(const unsigned short* __restrict__ n1,
                                                 const unsigned short* __restrict__ n2,
                                                 float* __restrict__ num) {
    int row = blockIdx.x;
    int l = threadIdx.x;
    const unsigned short* a = n1 + (size_t)row * DIM;
    const unsigned short* b = n2 + (size_t)row * DIM;
    float d = 0.f;
    #pragma unroll
    for (int j = 0; j < DIM / 64; ++j) {
        d += bf2f(a[l + j * 64]) * bf2f(b[l + j * 64]);
    }
    for (int off = 32; off; off >>= 1) d += __shfl_down(d, off);
    if (l == 0) num[row] = tstudent(d);
}

// ---------------- kernel 3: 256x256 8-wave MFMA GEMM, swizzled LDS ----------------
// LDS layout: [A buf0 32K][A buf1 32K][B buf0 32K][B buf1 32K] = 128 KiB.
// Tile storage: 256 rows x 64 bf16 (128 B row). Swizzle: 16B granule index
// seg_stored = seg_global ^ (row & 7)  -> conflict-free ds_read_b128.
// Staging keeps the linear LDS dest required by global_load_lds and applies
// the inverse swizzle on the per-lane GLOBAL source column (rule #21).

__device__ __forceinline__ void stage_tile(const unsigned short* gA, const unsigned short* gB,
                                           char* ldsA, char* ldsB, int t) {
    #pragma unroll
    for (int j = 0; j < 4; ++j) {
        __builtin_amdgcn_global_load_lds(
            (const __attribute__((address_space(1))) void*)(gA + (size_t)j * 64 * DIM),
            (__attribute__((address_space(3))) void*)(ldsA + t * 16 + j * 8192), 16, 0, 0);
        __builtin_amdgcn_global_load_lds(
            (const __attribute__((address_space(1))) void*)(gB + (size_t)j * 64 * DIM),
            (__attribute__((address_space(3))) void*)(ldsB + t * 16 + j * 8192), 16, 0, 0);
    }
}

#define PHASE_BARRIER()                                    \
    do {                                                   \
        __builtin_amdgcn_sched_barrier(0);                 \
        asm volatile("s_barrier" ::: "memory");            \
        __builtin_amdgcn_sched_barrier(0);                 \
    } while (0)

#define DRAIN_BARRIER()                                            \
    do {                                                           \
        __builtin_amdgcn_sched_barrier(0);                         \
        asm volatile("s_waitcnt vmcnt(0)\n\ts_barrier" ::: "memory"); \
        __builtin_amdgcn_sched_barrier(0);                         \
    } while (0)

#define DO_QUAD(mq)                                                                                         \
    {                                                                                                       \
        bf16x8 aA0 = *(const bf16x8*)(Ab + rbA + ((mq)*2    ) * 2048 + seg0);                               \
        bf16x8 aA1 = *(const bf16x8*)(Ab + rbA + ((mq)*2    ) * 2048 + seg1);                               \
        bf16x8 aB0 = *(const bf16x8*)(Ab + rbA + ((mq)*2 + 1) * 2048 + seg0);                               \
        bf16x8 aB1 = *(const bf16x8*)(Ab + rbA + ((mq)*2 + 1) * 2048 + seg1);                               \
        __builtin_amdgcn_s_setprio(1);                                                                      \
        _Pragma("unroll")                                                                                   \
        for (int n = 0; n < 4; ++n) {                                                                       \
            acc[(mq)*2][n]     = __builtin_amdgcn_mfma_f32_16x16x32_bf16(aA0, bfrag[n][0], acc[(mq)*2][n], 0, 0, 0);     \
            acc[(mq)*2][n]     = __builtin_amdgcn_mfma_f32_16x16x32_bf16(aA1, bfrag[n][1], acc[(mq)*2][n], 0, 0, 0);     \
            acc[(mq)*2 + 1][n] = __builtin_amdgcn_mfma_f32_16x16x32_bf16(aB0, bfrag[n][0], acc[(mq)*2 + 1][n], 0, 0, 0); \
            acc[(mq)*2 + 1][n] = __builtin_amdgcn_mfma_f32_16x16x32_bf16(aB1, bfrag[n][1], acc[(mq)*2 + 1][n], 0, 0, 0); \
        }                                                                                                   \
        __builtin_amdgcn_s_setprio(0);                                                                      \
    }

__global__ __launch_bounds__(512, 2) void gemm_kernel(const unsigned short* __restrict__ n1,
                                                      const unsigned short* __restrict__ n2,
                                                      float* __restrict__ partial) {
    extern __shared__ char smem[];
    int t = threadIdx.x;
    int l = t & 63;
    int w = t >> 6;
    int wr = w >> 2;   // 0..1 -> A half (128 rows)
    int wc = w & 3;    // 0..3 -> B quarter (64 cols)

    // XCD-aware bijective swizzle (1024 blocks, 1024 % 8 == 0)
    int bid = blockIdx.x;
    int swz = (bid & 7) * 128 + (bid >> 3);
    int br = swz >> 5;
    int bc = swz & 31;
    int rowbase = br * BM, colbase = bc * BN;

    // staging source: thread t covers LDS rows (t>>3)+64j, granule t&7;
    // inverse-swizzled global granule = (t&7) ^ ((t>>3)&7)
    int sr = t >> 3;
    int gcol0 = ((t & 7) ^ (sr & 7)) * 8;
    const unsigned short* Ag = n1 + (size_t)(rowbase + sr) * DIM + gcol0;
    const unsigned short* Bg = n2 + (size_t)(colbase + sr) * DIM + gcol0;

    f32x4 acc[8][4] = {};

    // read-side swizzled offsets
    int seg0 = (((l >> 4) + 0) ^ (l & 7)) * 16;
    int seg1 = (((l >> 4) + 4) ^ (l & 7)) * 16;
    int rbA = (wr * 128 + (l & 15)) * 128;
    int rbB = (wc * 64 + (l & 15)) * 128;

    // prologue: stage K-tile 0 into buf0, full drain
    stage_tile(Ag, Bg, smem, smem + 65536, t);
    DRAIN_BARRIER();

    for (int kt = 0; kt < KTILES; ++kt) {
        int db = kt & 1;
        const char* Ab = smem + db * 32768;
        const char* Bb = smem + 65536 + db * 32768;

        // ---- phase 0: issue next-tile stage, read all B frags + A m=0,1 ----
        if (kt + 1 < KTILES) {
            stage_tile(Ag + (kt + 1) * BK, Bg + (kt + 1) * BK,
                       smem + (db ^ 1) * 32768, smem + 65536 + (db ^ 1) * 32768, t);
        }
        bf16x8 bfrag[4][2];
        #pragma unroll
        for (int n = 0; n < 4; ++n) {
            bfrag[n][0] = *(const bf16x8*)(Bb + rbB + n * 2048 + seg0);
            bfrag[n][1] = *(const bf16x8*)(Bb + rbB + n * 2048 + seg1);
        }
        DO_QUAD(0)
        PHASE_BARRIER();
        // ---- phase 1 ----
        DO_QUAD(1)
        PHASE_BARRIER();
        // ---- phase 2 ----
        DO_QUAD(2)
        PHASE_BARRIER();
        // ---- phase 3 + counted drain (loads had ~3 phases in flight) ----
        DO_QUAD(3)
        DRAIN_BARRIER();
    }

    // ---------------- epilogue: t-Student + row sums ----------------
    // C/D map: row = wr*128 + m*16 + (l>>4)*4 + j (A-side), col = wc*64 + n*16 + (l&15) (B-side)
    float* red = (float*)smem;  // 256 rows x 4 wc
    #pragma unroll
    for (int m = 0; m < 8; ++m) {
        #pragma unroll
        for (int j = 0; j < 4; ++j) {
            float s = 0.f;
            #pragma unroll
            for (int n = 0; n < 4; ++n) s += tstudent(acc[m][n][j]);
            s += __shfl_xor(s, 1);
            s += __shfl_xor(s, 2);
            s += __shfl_xor(s, 4);
            s += __shfl_xor(s, 8);
            if ((l & 15) == 0) {
                int row = wr * 128 + m * 16 + (l >> 4) * 4 + j;
                red[row * 4 + wc] = s;
            }
        }
    }
    __syncthreads();
    if (t < BM) {
        partial[(size_t)bc * N_ROWS + rowbase + t] = red[t * 4 + 0] + red[t * 4 + 1] + red[t * 4 + 2] + red[t * 4 + 3];
    }
}

// ---------------- kernel 4: per-row denom + ratio, per-block sums ----------------
__global__ __launch_bounds__(256) void reduce_kernel(const float* __restrict__ partial,
                                                     const float* __restrict__ num,
                                                     float* __restrict__ blocksum) {
    int row = blockIdx.x * 256 + threadIdx.x;
    float d = 0.f;
    #pragma unroll 8
    for (int ct = 0; ct < NT2; ++ct) d += partial[(size_t)ct * N_ROWS + row];
    float s = num[row] / d;
    for (int off = 32; off; off >>= 1) s += __shfl_down(s, off);
    __shared__ float wsum[4];
    if ((threadIdx.x & 63) == 0) wsum[threadIdx.x >> 6] = s;
    __syncthreads();
    if (threadIdx.x == 0) blocksum[blockIdx.x] = wsum[0] + wsum[1] + wsum[2] + wsum[3];
}

// ---------------- kernel 5: final scalar ----------------
__global__ __launch_bounds__(64) void final_kernel(const float* __restrict__ blocksum,
                                                   float* __restrict__ out) {
    int l = threadIdx.x;
    float s = (l < 32) ? blocksum[l] : 0.f;
    for (int off = 32; off; off >>= 1) s += __shfl_down(s, off);
    if (l == 0) out[0] = -(s / (float)N_ROWS);
}

extern "C" void kernel_launch(void* const* d_in, const int* in_sizes, int n_in,
                              void* d_out, int out_size, void* d_ws, size_t ws_size,
                              hipStream_t stream) {
    const float* z1 = (const float*)d_in[0];
    const float* z2 = (const float*)d_in[1];
    char* ws = (char*)d_ws;
    const size_t n_bytes = (size_t)N_ROWS * DIM * 2;  // 12,582,912
    unsigned short* n1 = (unsigned short*)ws;
    unsigned short* n2 = (unsigned short*)(ws + n_bytes);
    float* num      = (float*)(ws + 2 * n_bytes);                         // 32 KB
    float* partial  = (float*)(ws + 2 * n_bytes + 32768);                 // 1 MB used
    float* blocksum = (float*)(ws + 2 * n_bytes + 32768 + 2097152);       // 128 B

    hipFuncSetAttribute((const void*)gemm_kernel,
                        hipFuncAttributeMaxDynamicSharedMemorySize, LDS_BYTES);

    norm_kernel<<<2 * N_ROWS, 256, 0, stream>>>(z1, z2, n1, n2);
    num_kernel<<<N_ROWS, 64, 0, stream>>>(n1, n2, num);
    gemm_kernel<<<NT2 * NT2, 512, LDS_BYTES, stream>>>(n1, n2, partial);
    reduce_kernel<<<N_ROWS / 256, 256, 0, stream>>>(partial, num, blocksum);
    final_kernel<<<1, 64, 0, stream>>>(blocksum, (float*)d_out);
}

// Round 3
// 129.025 us; speedup vs baseline: 1.3754x; 1.0922x over previous
//
#include <hip/hip_runtime.h>
#include <hip/hip_bf16.h>
#include <stdint.h>

#define N_ROWS 8192
#define DIM    768
#define BM     256
#define BN     256
#define BK     64
#define KTILES (DIM / BK)      // 12
#define NT2    (N_ROWS / BN)   // 32 col-tiles
#define LDS_BYTES 131072

typedef __attribute__((ext_vector_type(8))) short bf16x8;
typedef __attribute__((ext_vector_type(4))) float f32x4;

__device__ __forceinline__ float bf2f(unsigned short u) {
    union { uint32_t i; float f; } v; v.i = ((uint32_t)u) << 16; return v.f;
}
__device__ __forceinline__ unsigned short f2bf(float f) {
    union { float f; uint32_t i; } v; v.f = f;
    uint32_t u = v.i;
    return (unsigned short)((u + 0x7FFFu + ((u >> 16) & 1u)) >> 16);
}
__device__ __forceinline__ float tstudent(float c) {
    // (1 + 0.5*(1-c))^{-1.5} = t^{-1.5}, t = 1.5 - 0.5c
    float t = 1.5f - 0.5f * c;
    float r = rsqrtf(t);
    return r * r * r;
}

// ---------------- kernel 1: row L2-normalize fp32 -> bf16, fused diag numerator ----------------
__global__ __launch_bounds__(256) void norm_kernel(const float* __restrict__ z1,
                                                   const float* __restrict__ z2,
                                                   unsigned short* __restrict__ n1,
                                                   unsigned short* __restrict__ n2,
                                                   float* __restrict__ num) {
    int row = blockIdx.x;
    int t = threadIdx.x;
    const float* s1 = z1 + (size_t)row * DIM;
    const float* s2 = z2 + (size_t)row * DIM;
    float a0 = s1[t], a1 = s1[t + 256], a2 = s1[t + 512];
    float b0 = s2[t], b1 = s2[t + 256], b2 = s2[t + 512];
    float ss1 = a0 * a0 + a1 * a1 + a2 * a2;
    float ss2 = b0 * b0 + b1 * b1 + b2 * b2;
    float sd  = a0 * b0 + a1 * b1 + a2 * b2;
    for (int off = 32; off; off >>= 1) {
        ss1 += __shfl_down(ss1, off);
        ss2 += __shfl_down(ss2, off);
        sd  += __shfl_down(sd, off);
    }
    __shared__ float w1[4], w2[4], wd[4];
    __shared__ float sc1_s, sc2_s;
    if ((t & 63) == 0) { int wi = t >> 6; w1[wi] = ss1; w2[wi] = ss2; wd[wi] = sd; }
    __syncthreads();
    if (t == 0) {
        float nrm1 = fmaxf(sqrtf(w1[0] + w1[1] + w1[2] + w1[3]), 1e-8f);
        float nrm2 = fmaxf(sqrtf(w2[0] + w2[1] + w2[2] + w2[3]), 1e-8f);
        float dot  = wd[0] + wd[1] + wd[2] + wd[3];
        sc1_s = 1.0f / nrm1;
        sc2_s = 1.0f / nrm2;
        num[row] = tstudent(dot / (nrm1 * nrm2));
    }
    __syncthreads();
    float sc1 = sc1_s, sc2 = sc2_s;
    unsigned short* d1 = n1 + (size_t)row * DIM;
    unsigned short* d2 = n2 + (size_t)row * DIM;
    d1[t]       = f2bf(a0 * sc1);
    d1[t + 256] = f2bf(a1 * sc1);
    d1[t + 512] = f2bf(a2 * sc1);
    d2[t]       = f2bf(b0 * sc2);
    d2[t + 256] = f2bf(b1 * sc2);
    d2[t + 512] = f2bf(b2 * sc2);
}

// ---------------- kernel 2: 256x256 8-wave MFMA GEMM, 4-phase counted-vmcnt schedule ----------------
// LDS: [A buf0 32K][A buf1 32K][B buf0 32K][B buf1 32K] = 128 KiB.
// Tile: 256 rows x 64 bf16 (128 B/row). Swizzle: 16B-granule seg_stored = seg ^ (row & 7).
// Staging: linear LDS dest (global_load_lds) + inverse-swizzled global source column.
// Stage op j covers tile rows [64j, 64j+64). Issue order per K-tile: B0,B1,B2,B3,Aj0,Aj2,Aj1,Aj3,
// spread 2 per phase. Phase q consumes A rows [32q,32q+32) of each half ->
// counted waits: vmcnt(4) end of phase 1, vmcnt(2) end of phase 3. Never 0 in main loop.

__device__ __forceinline__ void stA(const unsigned short* Ag, char* ldsA, int t, int j) {
    __builtin_amdgcn_global_load_lds(
        (const __attribute__((address_space(1))) void*)(Ag + (size_t)j * 64 * DIM),
        (__attribute__((address_space(3))) void*)(ldsA + t * 16 + j * 8192), 16, 0, 0);
}

#define SB() __builtin_amdgcn_sched_barrier(0)
#define BAR_LGKM() do { SB(); asm volatile("s_barrier\n\ts_waitcnt lgkmcnt(0)" ::: "memory"); SB(); } while (0)
#define BAR()      do { SB(); asm volatile("s_barrier" ::: "memory"); SB(); } while (0)
#define VMW(n)     do { SB(); asm volatile("s_waitcnt vmcnt(" #n ")" ::: "memory"); SB(); } while (0)

#define READ_A(mq)                                                             \
    bf16x8 a0 = *(const bf16x8*)(Ab + rbA + ((mq)*2    ) * 2048 + seg0);       \
    bf16x8 a1 = *(const bf16x8*)(Ab + rbA + ((mq)*2    ) * 2048 + seg1);       \
    bf16x8 a2 = *(const bf16x8*)(Ab + rbA + ((mq)*2 + 1) * 2048 + seg0);       \
    bf16x8 a3 = *(const bf16x8*)(Ab + rbA + ((mq)*2 + 1) * 2048 + seg1);

#define MFMA_QUAD(mq)                                                                                       \
    __builtin_amdgcn_s_setprio(1);                                                                          \
    _Pragma("unroll")                                                                                       \
    for (int n = 0; n < 4; ++n) {                                                                           \
        acc[(mq)*2][n]     = __builtin_amdgcn_mfma_f32_16x16x32_bf16(a0, bfrag[n][0], acc[(mq)*2][n], 0, 0, 0);     \
        acc[(mq)*2][n]     = __builtin_amdgcn_mfma_f32_16x16x32_bf16(a1, bfrag[n][1], acc[(mq)*2][n], 0, 0, 0);     \
        acc[(mq)*2 + 1][n] = __builtin_amdgcn_mfma_f32_16x16x32_bf16(a2, bfrag[n][0], acc[(mq)*2 + 1][n], 0, 0, 0); \
        acc[(mq)*2 + 1][n] = __builtin_amdgcn_mfma_f32_16x16x32_bf16(a3, bfrag[n][1], acc[(mq)*2 + 1][n], 0, 0, 0); \
    }                                                                                                       \
    __builtin_amdgcn_s_setprio(0);

#define READ_B()                                                               \
    bf16x8 bfrag[4][2];                                                        \
    _Pragma("unroll")                                                          \
    for (int n = 0; n < 4; ++n) {                                              \
        bfrag[n][0] = *(const bf16x8*)(Bb + rbB + n * 2048 + seg0);            \
        bfrag[n][1] = *(const bf16x8*)(Bb + rbB + n * 2048 + seg1);            \
    }

__global__ __launch_bounds__(512, 2) void gemm_kernel(const unsigned short* __restrict__ n1,
                                                      const unsigned short* __restrict__ n2,
                                                      float* __restrict__ partial) {
    extern __shared__ char smem[];
    int t = threadIdx.x;
    int l = t & 63;
    int w = t >> 6;
    int wr = w >> 2;   // 0..1 -> A half (128 rows)
    int wc = w & 3;    // 0..3 -> B quarter (64 cols)

    // XCD-aware + L2 supertile mapping (1024 blocks, bijective):
    // xcd = bid&7 owns br stripe [xcd*4, xcd*4+4); within stripe, sweep bc in groups of 4.
    int bid = blockIdx.x;
    int xcd = bid & 7, idx = bid >> 3;
    int br = xcd * 4 + (idx & 3);
    int bc = (idx >> 4) * 4 + ((idx >> 2) & 3);
    int rowbase = br * BM, colbase = bc * BN;

    // staging source: thread t covers LDS rows (t>>3)+64j, granule t&7;
    // inverse-swizzled global granule = (t&7) ^ ((t>>3)&7)  (row&7 invariant under +64j)
    int sr = t >> 3;
    int gcol0 = ((t & 7) ^ (sr & 7)) * 8;
    const unsigned short* Ag = n1 + (size_t)(rowbase + sr) * DIM + gcol0;
    const unsigned short* Bg = n2 + (size_t)(colbase + sr) * DIM + gcol0;

    f32x4 acc[8][4] = {};

    // read-side swizzled offsets
    int seg0 = (((l >> 4) + 0) ^ (l & 7)) * 16;
    int seg1 = (((l >> 4) + 4) ^ (l & 7)) * 16;
    int rbA = (wr * 128 + (l & 15)) * 128;
    int rbB = (wc * 64 + (l & 15)) * 128;

    // prologue: stage K-tile 0 into buf0 (order: B0..B3, Aj0, Aj2, Aj1, Aj3)
    {
        char* A0 = smem;
        char* B0 = smem + 65536;
        stA(Bg, B0, t, 0); stA(Bg, B0, t, 1); stA(Bg, B0, t, 2); stA(Bg, B0, t, 3);
        stA(Ag, A0, t, 0); stA(Ag, A0, t, 2); stA(Ag, A0, t, 1); stA(Ag, A0, t, 3);
    }
    VMW(2);
    BAR();

    for (int kt = 0; kt < KTILES - 1; ++kt) {
        int db = kt & 1;
        const char* Ab = smem + db * 32768;
        const char* Bb = smem + 65536 + db * 32768;
        char* An = smem + (db ^ 1) * 32768;
        char* Bn = smem + 65536 + (db ^ 1) * 32768;
        const unsigned short* Agn = Ag + (kt + 1) * BK;
        const unsigned short* Bgn = Bg + (kt + 1) * BK;

        READ_B();
        {   // phase 0
            READ_A(0);
            stA(Bgn, Bn, t, 0); stA(Bgn, Bn, t, 1);
            BAR_LGKM();
            MFMA_QUAD(0);
            BAR();
        }
        {   // phase 1
            READ_A(1);
            stA(Bgn, Bn, t, 2); stA(Bgn, Bn, t, 3);
            VMW(4);
            BAR_LGKM();
            MFMA_QUAD(1);
            BAR();
        }
        {   // phase 2
            READ_A(2);
            stA(Agn, An, t, 0); stA(Agn, An, t, 2);
            BAR_LGKM();
            MFMA_QUAD(2);
            BAR();
        }
        {   // phase 3
            READ_A(3);
            stA(Agn, An, t, 1); stA(Agn, An, t, 3);
            VMW(2);
            BAR_LGKM();
            MFMA_QUAD(3);
            BAR();
        }
    }
    {   // peeled last K-tile (kt = KTILES-1, odd => buf1), no staging, tail drain
        const char* Ab = smem + ((KTILES - 1) & 1) * 32768;
        const char* Bb = smem + 65536 + ((KTILES - 1) & 1) * 32768;
        READ_B();
        {   // phase 0
            READ_A(0);
            BAR_LGKM();
            MFMA_QUAD(0);
            BAR();
        }
        {   // phase 1 — drain late-A of this tile before phase 2 reads it
            READ_A(1);
            VMW(0);
            BAR_LGKM();
            MFMA_QUAD(1);
            BAR();
        }
        {   // phase 2
            READ_A(2);
            BAR_LGKM();
            MFMA_QUAD(2);
            BAR();
        }
        {   // phase 3
            READ_A(3);
            BAR_LGKM();
            MFMA_QUAD(3);
            BAR();
        }
    }

    // ---------------- epilogue: t-Student + row sums ----------------
    // C/D map: row = wr*128 + m*16 + (l>>4)*4 + j (A-side), col = wc*64 + n*16 + (l&15) (B-side)
    float* red = (float*)smem;  // 256 rows x 4 wc
    #pragma unroll
    for (int m = 0; m < 8; ++m) {
        #pragma unroll
        for (int j = 0; j < 4; ++j) {
            float s = 0.f;
            #pragma unroll
            for (int n = 0; n < 4; ++n) s += tstudent(acc[m][n][j]);
            s += __shfl_xor(s, 1);
            s += __shfl_xor(s, 2);
            s += __shfl_xor(s, 4);
            s += __shfl_xor(s, 8);
            if ((l & 15) == 0) {
                int row = wr * 128 + m * 16 + (l >> 4) * 4 + j;
                red[row * 4 + wc] = s;
            }
        }
    }
    __syncthreads();
    if (t < BM) {
        partial[(size_t)bc * N_ROWS + rowbase + t] = red[t * 4 + 0] + red[t * 4 + 1] + red[t * 4 + 2] + red[t * 4 + 3];
    }
}

// ---------------- kernel 3: per-row denom + ratio, per-block sums ----------------
__global__ __launch_bounds__(256) void reduce_kernel(const float* __restrict__ partial,
                                                     const float* __restrict__ num,
                                                     float* __restrict__ blocksum) {
    int row = blockIdx.x * 256 + threadIdx.x;
    float d = 0.f;
    #pragma unroll 8
    for (int ct = 0; ct < NT2; ++ct) d += partial[(size_t)ct * N_ROWS + row];
    float s = num[row] / d;
    for (int off = 32; off; off >>= 1) s += __shfl_down(s, off);
    __shared__ float wsum[4];
    if ((threadIdx.x & 63) == 0) wsum[threadIdx.x >> 6] = s;
    __syncthreads();
    if (threadIdx.x == 0) blocksum[blockIdx.x] = wsum[0] + wsum[1] + wsum[2] + wsum[3];
}

// ---------------- kernel 4: final scalar ----------------
__global__ __launch_bounds__(64) void final_kernel(const float* __restrict__ blocksum,
                                                   float* __restrict__ out) {
    int l = threadIdx.x;
    float s = (l < 32) ? blocksum[l] : 0.f;
    for (int off = 32; off; off >>= 1) s += __shfl_down(s, off);
    if (l == 0) out[0] = -(s / (float)N_ROWS);
}

extern "C" void kernel_launch(void* const* d_in, const int* in_sizes, int n_in,
                              void* d_out, int out_size, void* d_ws, size_t ws_size,
                              hipStream_t stream) {
    const float* z1 = (const float*)d_in[0];
    const float* z2 = (const float*)d_in[1];
    char* ws = (char*)d_ws;
    const size_t n_bytes = (size_t)N_ROWS * DIM * 2;  // 12,582,912
    unsigned short* n1 = (unsigned short*)ws;
    unsigned short* n2 = (unsigned short*)(ws + n_bytes);
    float* num      = (float*)(ws + 2 * n_bytes);                         // 32 KB
    float* partial  = (float*)(ws + 2 * n_bytes + 32768);                 // 1 MB used
    float* blocksum = (float*)(ws + 2 * n_bytes + 32768 + 2097152);       // 128 B

    hipFuncSetAttribute((const void*)gemm_kernel,
                        hipFuncAttributeMaxDynamicSharedMemorySize, LDS_BYTES);

    norm_kernel<<<N_ROWS, 256, 0, stream>>>(z1, z2, n1, n2, num);
    gemm_kernel<<<NT2 * NT2, 512, LDS_BYTES, stream>>>(n1, n2, partial);
    reduce_kernel<<<N_ROWS / 256, 256, 0, stream>>>(partial, num, blocksum);
    final_kernel<<<1, 64, 0, stream>>>(blocksum, (float*)d_out);
}

// Round 4
// 128.868 us; speedup vs baseline: 1.3770x; 1.0012x over previous
//
#include <hip/hip_runtime.h>
#include <hip/hip_bf16.h>
#include <stdint.h>

#define N_ROWS 8192
#define DIM    768
#define BM     256
#define BN     256
#define BK     64
#define KTILES (DIM / BK)      // 12
#define NT2    (N_ROWS / BN)   // 32 col-tiles
#define LDS_BYTES 131072

typedef __attribute__((ext_vector_type(8))) short bf16x8;
typedef __attribute__((ext_vector_type(4))) float f32x4;

__device__ __forceinline__ float bf2f(unsigned short u) {
    union { uint32_t i; float f; } v; v.i = ((uint32_t)u) << 16; return v.f;
}
__device__ __forceinline__ unsigned short f2bf(float f) {
    union { float f; uint32_t i; } v; v.f = f;
    uint32_t u = v.i;
    return (unsigned short)((u + 0x7FFFu + ((u >> 16) & 1u)) >> 16);
}
__device__ __forceinline__ float tstudent(float c) {
    // (1 + 0.5*(1-c))^{-1.5} = t^{-1.5}, t = 1.5 - 0.5c
    float t = 1.5f - 0.5f * c;
    float r = rsqrtf(t);
    return r * r * r;
}

// ---------------- kernel 1: row L2-normalize fp32 -> bf16, fused diag numerator ----------------
__global__ __launch_bounds__(256) void norm_kernel(const float* __restrict__ z1,
                                                   const float* __restrict__ z2,
                                                   unsigned short* __restrict__ n1,
                                                   unsigned short* __restrict__ n2,
                                                   float* __restrict__ num) {
    int row = blockIdx.x;
    int t = threadIdx.x;
    const float* s1 = z1 + (size_t)row * DIM;
    const float* s2 = z2 + (size_t)row * DIM;
    float a0 = s1[t], a1 = s1[t + 256], a2 = s1[t + 512];
    float b0 = s2[t], b1 = s2[t + 256], b2 = s2[t + 512];
    float ss1 = a0 * a0 + a1 * a1 + a2 * a2;
    float ss2 = b0 * b0 + b1 * b1 + b2 * b2;
    float sd  = a0 * b0 + a1 * b1 + a2 * b2;
    for (int off = 32; off; off >>= 1) {
        ss1 += __shfl_down(ss1, off);
        ss2 += __shfl_down(ss2, off);
        sd  += __shfl_down(sd, off);
    }
    __shared__ float w1[4], w2[4], wd[4];
    __shared__ float sc1_s, sc2_s;
    if ((t & 63) == 0) { int wi = t >> 6; w1[wi] = ss1; w2[wi] = ss2; wd[wi] = sd; }
    __syncthreads();
    if (t == 0) {
        float nrm1 = fmaxf(sqrtf(w1[0] + w1[1] + w1[2] + w1[3]), 1e-8f);
        float nrm2 = fmaxf(sqrtf(w2[0] + w2[1] + w2[2] + w2[3]), 1e-8f);
        float dot  = wd[0] + wd[1] + wd[2] + wd[3];
        sc1_s = 1.0f / nrm1;
        sc2_s = 1.0f / nrm2;
        num[row] = tstudent(dot / (nrm1 * nrm2));
    }
    __syncthreads();
    float sc1 = sc1_s, sc2 = sc2_s;
    unsigned short* d1 = n1 + (size_t)row * DIM;
    unsigned short* d2 = n2 + (size_t)row * DIM;
    d1[t]       = f2bf(a0 * sc1);
    d1[t + 256] = f2bf(a1 * sc1);
    d1[t + 512] = f2bf(a2 * sc1);
    d2[t]       = f2bf(b0 * sc2);
    d2[t + 256] = f2bf(b1 * sc2);
    d2[t + 512] = f2bf(b2 * sc2);
}

// ---------------- kernel 2: 256x256 8-wave MFMA GEMM, 4-phase counted-vmcnt schedule ----------------
// LDS: [A buf0 32K][A buf1 32K][B buf0 32K][B buf1 32K] = 128 KiB.
// Tile: 256 rows x 64 bf16 (128 B/row). Swizzle: 16B-granule seg_stored = seg ^ (row & 7).
// Staging: linear LDS dest (global_load_lds) + inverse-swizzled global source column.
// Stage op j covers tile rows [64j, 64j+64). Issue order per K-tile: B0,B1,B2,B3,Aj0,Aj2,Aj1,Aj3,
// spread 2 per phase. Phase q consumes A rows [32q,32q+32) of each half ->
// counted waits: vmcnt(4) end of phase 1, vmcnt(2) end of phase 3. Never 0 in main loop.
// NOTE (round 4): no sched_barrier / no blanket lgkmcnt — compiler emits fine-grained
// lgkmcnt interleaved with MFMA (m141/m97 lesson). Only counted vmcnt stays explicit
// (compiler can't track global_load_lds -> LDS-read deps), placed BEFORE the barrier
// so the barrier publishes "my guarded loads landed" to all waves.

__device__ __forceinline__ void stA(const unsigned short* Ag, char* ldsA, int t, int j) {
    __builtin_amdgcn_global_load_lds(
        (const __attribute__((address_space(1))) void*)(Ag + (size_t)j * 64 * DIM),
        (__attribute__((address_space(3))) void*)(ldsA + t * 16 + j * 8192), 16, 0, 0);
}

#define BAR()  __builtin_amdgcn_s_barrier()
#define VMW(n) asm volatile("s_waitcnt vmcnt(" #n ")" ::: "memory")

#define READ_A(mq)                                                             \
    bf16x8 a0 = *(const bf16x8*)(Ab + rbA + ((mq)*2    ) * 2048 + seg0);       \
    bf16x8 a1 = *(const bf16x8*)(Ab + rbA + ((mq)*2    ) * 2048 + seg1);       \
    bf16x8 a2 = *(const bf16x8*)(Ab + rbA + ((mq)*2 + 1) * 2048 + seg0);       \
    bf16x8 a3 = *(const bf16x8*)(Ab + rbA + ((mq)*2 + 1) * 2048 + seg1);

#define MFMA_QUAD(mq)                                                                                       \
    __builtin_amdgcn_s_setprio(1);                                                                          \
    _Pragma("unroll")                                                                                       \
    for (int n = 0; n < 4; ++n) {                                                                           \
        acc[(mq)*2][n]     = __builtin_amdgcn_mfma_f32_16x16x32_bf16(a0, bfrag[n][0], acc[(mq)*2][n], 0, 0, 0);     \
        acc[(mq)*2][n]     = __builtin_amdgcn_mfma_f32_16x16x32_bf16(a1, bfrag[n][1], acc[(mq)*2][n], 0, 0, 0);     \
        acc[(mq)*2 + 1][n] = __builtin_amdgcn_mfma_f32_16x16x32_bf16(a2, bfrag[n][0], acc[(mq)*2 + 1][n], 0, 0, 0); \
        acc[(mq)*2 + 1][n] = __builtin_amdgcn_mfma_f32_16x16x32_bf16(a3, bfrag[n][1], acc[(mq)*2 + 1][n], 0, 0, 0); \
    }                                                                                                       \
    __builtin_amdgcn_s_setprio(0);

#define READ_B()                                                               \
    bf16x8 bfrag[4][2];                                                        \
    _Pragma("unroll")                                                          \
    for (int n = 0; n < 4; ++n) {                                              \
        bfrag[n][0] = *(const bf16x8*)(Bb + rbB + n * 2048 + seg0);            \
        bfrag[n][1] = *(const bf16x8*)(Bb + rbB + n * 2048 + seg1);            \
    }

__global__ __launch_bounds__(512, 2) void gemm_kernel(const unsigned short* __restrict__ n1,
                                                      const unsigned short* __restrict__ n2,
                                                      float* __restrict__ partial) {
    extern __shared__ char smem[];
    int t = threadIdx.x;
    int l = t & 63;
    int w = t >> 6;
    int wr = w >> 2;   // 0..1 -> A half (128 rows)
    int wc = w & 3;    // 0..3 -> B quarter (64 cols)

    // XCD-aware + L2 supertile mapping (1024 blocks, bijective):
    // xcd = bid&7 owns br stripe [xcd*4, xcd*4+4); within stripe, sweep bc in groups of 4.
    int bid = blockIdx.x;
    int xcd = bid & 7, idx = bid >> 3;
    int br = xcd * 4 + (idx & 3);
    int bc = (idx >> 4) * 4 + ((idx >> 2) & 3);
    int rowbase = br * BM, colbase = bc * BN;

    // staging source: thread t covers LDS rows (t>>3)+64j, granule t&7;
    // inverse-swizzled global granule = (t&7) ^ ((t>>3)&7)  (row&7 invariant under +64j)
    int sr = t >> 3;
    int gcol0 = ((t & 7) ^ (sr & 7)) * 8;
    const unsigned short* Ag = n1 + (size_t)(rowbase + sr) * DIM + gcol0;
    const unsigned short* Bg = n2 + (size_t)(colbase + sr) * DIM + gcol0;

    f32x4 acc[8][4] = {};

    // read-side swizzled offsets
    int seg0 = (((l >> 4) + 0) ^ (l & 7)) * 16;
    int seg1 = (((l >> 4) + 4) ^ (l & 7)) * 16;
    int rbA = (wr * 128 + (l & 15)) * 128;
    int rbB = (wc * 64 + (l & 15)) * 128;

    // prologue: stage K-tile 0 into buf0 (order: B0..B3, Aj0, Aj2, Aj1, Aj3)
    {
        char* A0 = smem;
        char* B0 = smem + 65536;
        stA(Bg, B0, t, 0); stA(Bg, B0, t, 1); stA(Bg, B0, t, 2); stA(Bg, B0, t, 3);
        stA(Ag, A0, t, 0); stA(Ag, A0, t, 2); stA(Ag, A0, t, 1); stA(Ag, A0, t, 3);
    }
    VMW(2);
    BAR();

    for (int kt = 0; kt < KTILES - 1; ++kt) {
        int db = kt & 1;
        const char* Ab = smem + db * 32768;
        const char* Bb = smem + 65536 + db * 32768;
        char* An = smem + (db ^ 1) * 32768;
        char* Bn = smem + 65536 + (db ^ 1) * 32768;
        const unsigned short* Agn = Ag + (kt + 1) * BK;
        const unsigned short* Bgn = Bg + (kt + 1) * BK;

        READ_B();
        {   // phase 0
            READ_A(0);
            stA(Bgn, Bn, t, 0); stA(Bgn, Bn, t, 1);
            BAR();
            MFMA_QUAD(0);
            BAR();
        }
        {   // phase 1
            READ_A(1);
            stA(Bgn, Bn, t, 2); stA(Bgn, Bn, t, 3);
            VMW(4);
            BAR();
            MFMA_QUAD(1);
            BAR();
        }
        {   // phase 2
            READ_A(2);
            stA(Agn, An, t, 0); stA(Agn, An, t, 2);
            BAR();
            MFMA_QUAD(2);
            BAR();
        }
        {   // phase 3
            READ_A(3);
            stA(Agn, An, t, 1); stA(Agn, An, t, 3);
            VMW(2);
            BAR();
            MFMA_QUAD(3);
            BAR();
        }
    }
    {   // peeled last K-tile (kt = KTILES-1, odd => buf1), no staging, tail drain
        const char* Ab = smem + ((KTILES - 1) & 1) * 32768;
        const char* Bb = smem + 65536 + ((KTILES - 1) & 1) * 32768;
        READ_B();
        {   // phase 0
            READ_A(0);
            BAR();
            MFMA_QUAD(0);
            BAR();
        }
        {   // phase 1 — drain late-A of this tile before phase 2 reads it
            READ_A(1);
            VMW(0);
            BAR();
            MFMA_QUAD(1);
            BAR();
        }
        {   // phase 2
            READ_A(2);
            BAR();
            MFMA_QUAD(2);
            BAR();
        }
        {   // phase 3
            READ_A(3);
            BAR();
            MFMA_QUAD(3);
            BAR();
        }
    }

    // ---------------- epilogue: t-Student + row sums ----------------
    // C/D map: row = wr*128 + m*16 + (l>>4)*4 + j (A-side), col = wc*64 + n*16 + (l&15) (B-side)
    float* red = (float*)smem;  // 256 rows x 4 wc
    __syncthreads();           // all LDS reads of the K-loop done before reuse as 'red'
    #pragma unroll
    for (int m = 0; m < 8; ++m) {
        #pragma unroll
        for (int j = 0; j < 4; ++j) {
            float s = 0.f;
            #pragma unroll
            for (int n = 0; n < 4; ++n) s += tstudent(acc[m][n][j]);
            s += __shfl_xor(s, 1);
            s += __shfl_xor(s, 2);
            s += __shfl_xor(s, 4);
            s += __shfl_xor(s, 8);
            if ((l & 15) == 0) {
                int row = wr * 128 + m * 16 + (l >> 4) * 4 + j;
                red[row * 4 + wc] = s;
            }
        }
    }
    __syncthreads();
    if (t < BM) {
        partial[(size_t)bc * N_ROWS + rowbase + t] = red[t * 4 + 0] + red[t * 4 + 1] + red[t * 4 + 2] + red[t * 4 + 3];
    }
}

// ---------------- kernel 3: per-row denom + ratio, per-block sums ----------------
__global__ __launch_bounds__(256) void reduce_kernel(const float* __restrict__ partial,
                                                     const float* __restrict__ num,
                                                     float* __restrict__ blocksum) {
    int row = blockIdx.x * 256 + threadIdx.x;
    float d = 0.f;
    #pragma unroll 8
    for (int ct = 0; ct < NT2; ++ct) d += partial[(size_t)ct * N_ROWS + row];
    float s = num[row] / d;
    for (int off = 32; off; off >>= 1) s += __shfl_down(s, off);
    __shared__ float wsum[4];
    if ((threadIdx.x & 63) == 0) wsum[threadIdx.x >> 6] = s;
    __syncthreads();
    if (threadIdx.x == 0) blocksum[blockIdx.x] = wsum[0] + wsum[1] + wsum[2] + wsum[3];
}

// ---------------- kernel 4: final scalar ----------------
__global__ __launch_bounds__(64) void final_kernel(const float* __restrict__ blocksum,
                                                   float* __restrict__ out) {
    int l = threadIdx.x;
    float s = (l < 32) ? blocksum[l] : 0.f;
    for (int off = 32; off; off >>= 1) s += __shfl_down(s, off);
    if (l == 0) out[0] = -(s / (float)N_ROWS);
}

extern "C" void kernel_launch(void* const* d_in, const int* in_sizes, int n_in,
                              void* d_out, int out_size, void* d_ws, size_t ws_size,
                              hipStream_t stream) {
    const float* z1 = (const float*)d_in[0];
    const float* z2 = (const float*)d_in[1];
    char* ws = (char*)d_ws;
    const size_t n_bytes = (size_t)N_ROWS * DIM * 2;  // 12,582,912
    unsigned short* n1 = (unsigned short*)ws;
    unsigned short* n2 = (unsigned short*)(ws + n_bytes);
    float* num      = (float*)(ws + 2 * n_bytes);                         // 32 KB
    float* partial  = (float*)(ws + 2 * n_bytes + 32768);                 // 1 MB used
    float* blocksum = (float*)(ws + 2 * n_bytes + 32768 + 2097152);       // 128 B

    hipFuncSetAttribute((const void*)gemm_kernel,
                        hipFuncAttributeMaxDynamicSharedMemorySize, LDS_BYTES);

    norm_kernel<<<N_ROWS, 256, 0, stream>>>(z1, z2, n1, n2, num);
    gemm_kernel<<<NT2 * NT2, 512, LDS_BYTES, stream>>>(n1, n2, partial);
    reduce_kernel<<<N_ROWS / 256, 256, 0, stream>>>(partial, num, blocksum);
    final_kernel<<<1, 64, 0, stream>>>(blocksum, (float*)d_out);
}

// Round 5
// 125.550 us; speedup vs baseline: 1.4134x; 1.0264x over previous
//
#include <hip/hip_runtime.h>
#include <hip/hip_bf16.h>
#include <stdint.h>

#define N_ROWS 8192
#define DIM    768
#define BM     256
#define BN     256
#define BK     64
#define KTILES (DIM / BK)      // 12
#define NT2    (N_ROWS / BN)   // 32 col-tiles
#define LDS_BYTES 131072

typedef __attribute__((ext_vector_type(8))) short bf16x8;
typedef __attribute__((ext_vector_type(4))) float f32x4;

__device__ __forceinline__ float bf2f(unsigned short u) {
    union { uint32_t i; float f; } v; v.i = ((uint32_t)u) << 16; return v.f;
}
__device__ __forceinline__ unsigned short f2bf(float f) {
    union { float f; uint32_t i; } v; v.f = f;
    uint32_t u = v.i;
    return (unsigned short)((u + 0x7FFFu + ((u >> 16) & 1u)) >> 16);
}
__device__ __forceinline__ float tstudent(float c) {
    // (1 + 0.5*(1-c))^{-1.5} = t^{-1.5}, t = 1.5 - 0.5c
    float t = 1.5f - 0.5f * c;
    float r = rsqrtf(t);
    return r * r * r;
}

// ---------------- kernel 1: row L2-normalize fp32 -> bf16, fused diag numerator ----------------
__global__ __launch_bounds__(256) void norm_kernel(const float* __restrict__ z1,
                                                   const float* __restrict__ z2,
                                                   unsigned short* __restrict__ n1,
                                                   unsigned short* __restrict__ n2,
                                                   float* __restrict__ num) {
    int row = blockIdx.x;
    int t = threadIdx.x;
    const float* s1 = z1 + (size_t)row * DIM;
    const float* s2 = z2 + (size_t)row * DIM;
    float a0 = s1[t], a1 = s1[t + 256], a2 = s1[t + 512];
    float b0 = s2[t], b1 = s2[t + 256], b2 = s2[t + 512];
    float ss1 = a0 * a0 + a1 * a1 + a2 * a2;
    float ss2 = b0 * b0 + b1 * b1 + b2 * b2;
    float sd  = a0 * b0 + a1 * b1 + a2 * b2;
    for (int off = 32; off; off >>= 1) {
        ss1 += __shfl_down(ss1, off);
        ss2 += __shfl_down(ss2, off);
        sd  += __shfl_down(sd, off);
    }
    __shared__ float w1[4], w2[4], wd[4];
    __shared__ float sc1_s, sc2_s;
    if ((t & 63) == 0) { int wi = t >> 6; w1[wi] = ss1; w2[wi] = ss2; wd[wi] = sd; }
    __syncthreads();
    if (t == 0) {
        float nrm1 = fmaxf(sqrtf(w1[0] + w1[1] + w1[2] + w1[3]), 1e-8f);
        float nrm2 = fmaxf(sqrtf(w2[0] + w2[1] + w2[2] + w2[3]), 1e-8f);
        float dot  = wd[0] + wd[1] + wd[2] + wd[3];
        sc1_s = 1.0f / nrm1;
        sc2_s = 1.0f / nrm2;
        num[row] = tstudent(dot / (nrm1 * nrm2));
    }
    __syncthreads();
    float sc1 = sc1_s, sc2 = sc2_s;
    unsigned short* d1 = n1 + (size_t)row * DIM;
    unsigned short* d2 = n2 + (size_t)row * DIM;
    d1[t]       = f2bf(a0 * sc1);
    d1[t + 256] = f2bf(a1 * sc1);
    d1[t + 512] = f2bf(a2 * sc1);
    d2[t]       = f2bf(b0 * sc2);
    d2[t + 256] = f2bf(b1 * sc2);
    d2[t + 512] = f2bf(b2 * sc2);
}

// ---------------- kernel 2: 256x256 8-wave MFMA GEMM, pipelined read-ahead schedule ----------------
// LDS: [A buf0 32K][A buf1 32K][B buf0 32K][B buf1 32K] = 128 KiB.
// Tile: 256 rows x 64 bf16 (128 B/row). Swizzle: 16B-granule seg_stored = seg ^ (row & 7).
// Staging: linear LDS dest (global_load_lds) + inverse-swizzled global source column.
//
// ROUND-5 SCHEDULE: fragment ds_reads are issued ONE PHASE AHEAD of their MFMA use
// (double-buffered A-frag register sets aS0/aS1; B seg0 read at ph3 of the PREVIOUS
// tile, B seg1 at ph0 of the current tile with seg0-first MFMA ordering). Only 2
// barriers per K-tile (at the counted-vmcnt publish points ph1/ph3). Stage issue
// order per tile kt (staging kt+1): ph0:B0,B1  ph1:B2,B3  ph2:A0,A2  ph3:A1,A3.
// Per-wave vmcnt ledger (steady state, entering ph0: [A1,A3(kt)]):
//   ph1: +B2,B3 -> 6 outstanding; VMW(4) drains A1,A3(kt) (rows 64..127/192..255,
//        needed by ph1's q2-reads and ph2's q3-reads); BAR publishes.
//   ph3: +A1,A3(kt+1) -> 8; VMW(2) drains B0..B3,A0,A2(kt+1) (needed by ph3's
//        B-seg0(kt+1) and A-q0(kt+1) reads); leaves [A1,A3(kt+1)] = invariant.
// WAR safety with 2 barriers/tile: each LDS buffer's last ds_read completes (lgkm'd
// at the following MFMA) at least one barrier before any stage-write re-targets it.

__device__ __forceinline__ void stA(const unsigned short* Ag, char* ldsA, int t, int j) {
    __builtin_amdgcn_global_load_lds(
        (const __attribute__((address_space(1))) void*)(Ag + (size_t)j * 64 * DIM),
        (__attribute__((address_space(3))) void*)(ldsA + t * 16 + j * 8192), 16, 0, 0);
}

#define BAR()  asm volatile("s_barrier" ::: "memory")
#define VMW(n) asm volatile("s_waitcnt vmcnt(" #n ")" ::: "memory")

#define READ_AQ(dst, Abase, q)                                                  \
    dst[0] = *(const bf16x8*)((Abase) + rbA + ((q)*2    ) * 2048 + seg0);       \
    dst[1] = *(const bf16x8*)((Abase) + rbA + ((q)*2    ) * 2048 + seg1);       \
    dst[2] = *(const bf16x8*)((Abase) + rbA + ((q)*2 + 1) * 2048 + seg0);       \
    dst[3] = *(const bf16x8*)((Abase) + rbA + ((q)*2 + 1) * 2048 + seg1);

#define READ_BSEG0(dst, Bbase)                                                  \
    dst[0] = *(const bf16x8*)((Bbase) + rbB + 0 * 2048 + seg0);                 \
    dst[1] = *(const bf16x8*)((Bbase) + rbB + 1 * 2048 + seg0);                 \
    dst[2] = *(const bf16x8*)((Bbase) + rbB + 2 * 2048 + seg0);                 \
    dst[3] = *(const bf16x8*)((Bbase) + rbB + 3 * 2048 + seg0);

#define READ_BSEG1(Bbase)                                                       \
    bSeg1[0] = *(const bf16x8*)((Bbase) + rbB + 0 * 2048 + seg1);               \
    bSeg1[1] = *(const bf16x8*)((Bbase) + rbB + 1 * 2048 + seg1);               \
    bSeg1[2] = *(const bf16x8*)((Bbase) + rbB + 2 * 2048 + seg1);               \
    bSeg1[3] = *(const bf16x8*)((Bbase) + rbB + 3 * 2048 + seg1);

// seg0-first ordering: the 8 seg0 MFMAs run on frags read a full phase ago,
// covering the just-issued seg1/B reads' latency.
#define MFMA_Q(q, AS, BS0)                                                                                   \
    __builtin_amdgcn_s_setprio(1);                                                                           \
    _Pragma("unroll")                                                                                        \
    for (int n = 0; n < 4; ++n) {                                                                            \
        acc[(q)*2][n]     = __builtin_amdgcn_mfma_f32_16x16x32_bf16(AS[0], BS0[n], acc[(q)*2][n], 0, 0, 0);      \
        acc[(q)*2 + 1][n] = __builtin_amdgcn_mfma_f32_16x16x32_bf16(AS[2], BS0[n], acc[(q)*2 + 1][n], 0, 0, 0);  \
    }                                                                                                        \
    _Pragma("unroll")                                                                                        \
    for (int n = 0; n < 4; ++n) {                                                                            \
        acc[(q)*2][n]     = __builtin_amdgcn_mfma_f32_16x16x32_bf16(AS[1], bSeg1[n], acc[(q)*2][n], 0, 0, 0);    \
        acc[(q)*2 + 1][n] = __builtin_amdgcn_mfma_f32_16x16x32_bf16(AS[3], bSeg1[n], acc[(q)*2 + 1][n], 0, 0, 0); \
    }                                                                                                        \
    __builtin_amdgcn_s_setprio(0);

#define TILE(kt, B0c, B0n, PAR)                                                 \
    {                                                                           \
        const char* Ab  = smem + (PAR) * 32768;                                 \
        const char* Bb  = smem + 65536 + (PAR) * 32768;                         \
        const char* AbN = smem + ((PAR) ^ 1) * 32768;                           \
        const char* BbN = smem + 65536 + ((PAR) ^ 1) * 32768;                   \
        char* AnW = smem + ((PAR) ^ 1) * 32768;                                 \
        char* BnW = smem + 65536 + ((PAR) ^ 1) * 32768;                         \
        const unsigned short* Agn = Ag + ((kt) + 1) * BK;                       \
        const unsigned short* Bgn = Bg + ((kt) + 1) * BK;                       \
        /* ph0 */                                                               \
        stA(Bgn, BnW, t, 0); stA(Bgn, BnW, t, 1);                               \
        READ_BSEG1(Bb);                                                         \
        READ_AQ(aS1, Ab, 1);                                                    \
        MFMA_Q(0, aS0, B0c);                                                    \
        /* ph1 */                                                               \
        stA(Bgn, BnW, t, 2); stA(Bgn, BnW, t, 3);                               \
        VMW(4); BAR();                                                          \
        READ_AQ(aS0, Ab, 2);                                                    \
        MFMA_Q(1, aS1, B0c);                                                    \
        /* ph2 */                                                               \
        stA(Agn, AnW, t, 0); stA(Agn, AnW, t, 2);                               \
        READ_AQ(aS1, Ab, 3);                                                    \
        MFMA_Q(2, aS0, B0c);                                                    \
        /* ph3 */                                                               \
        stA(Agn, AnW, t, 1); stA(Agn, AnW, t, 3);                               \
        VMW(2); BAR();                                                          \
        READ_BSEG0(B0n, BbN);                                                   \
        READ_AQ(aS0, AbN, 0);                                                   \
        MFMA_Q(3, aS1, B0c);                                                    \
    }

__global__ __launch_bounds__(512, 2) void gemm_kernel(const unsigned short* __restrict__ n1,
                                                      const unsigned short* __restrict__ n2,
                                                      float* __restrict__ partial) {
    extern __shared__ char smem[];
    int t = threadIdx.x;
    int l = t & 63;
    int w = t >> 6;
    int wr = w >> 2;   // 0..1 -> A half (128 rows)
    int wc = w & 3;    // 0..3 -> B quarter (64 cols)

    // XCD-aware + L2 supertile mapping (1024 blocks, bijective):
    int bid = blockIdx.x;
    int xcd = bid & 7, idx = bid >> 3;
    int br = xcd * 4 + (idx & 3);
    int bc = (idx >> 4) * 4 + ((idx >> 2) & 3);
    int rowbase = br * BM, colbase = bc * BN;

    // staging source: thread t covers LDS rows (t>>3)+64j, granule t&7;
    // inverse-swizzled global granule = (t&7) ^ ((t>>3)&7)
    int sr = t >> 3;
    int gcol0 = ((t & 7) ^ (sr & 7)) * 8;
    const unsigned short* Ag = n1 + (size_t)(rowbase + sr) * DIM + gcol0;
    const unsigned short* Bg = n2 + (size_t)(colbase + sr) * DIM + gcol0;

    f32x4 acc[8][4] = {};

    // read-side swizzled offsets
    int seg0 = (((l >> 4) + 0) ^ (l & 7)) * 16;
    int seg1 = (((l >> 4) + 4) ^ (l & 7)) * 16;
    int rbA = (wr * 128 + (l & 15)) * 128;
    int rbB = (wc * 64 + (l & 15)) * 128;

    // fragment register sets
    bf16x8 aS0[4], aS1[4];       // A-quad frags, ping-pong by phase parity
    bf16x8 bB0s0[4], bB1s0[4];   // B seg0 frags, ping-pong by tile parity
    bf16x8 bSeg1[4];             // B seg1 frags, single-buffered (dead by next ph0)

    // prologue: stage K-tile 0 (order B0,B1,B2,B3,A0,A2,A1,A3), publish first 6
    {
        char* A0b = smem;
        char* B0b = smem + 65536;
        stA(Bg, B0b, t, 0); stA(Bg, B0b, t, 1); stA(Bg, B0b, t, 2); stA(Bg, B0b, t, 3);
        stA(Ag, A0b, t, 0); stA(Ag, A0b, t, 2); stA(Ag, A0b, t, 1); stA(Ag, A0b, t, 3);
    }
    VMW(2);
    BAR();
    READ_BSEG0(bB0s0, smem + 65536);
    READ_AQ(aS0, smem, 0);

    for (int kt = 0; kt < 10; kt += 2) {
        TILE(kt,     bB0s0, bB1s0, 0);
        TILE(kt + 1, bB1s0, bB0s0, 1);
    }
    TILE(10, bB0s0, bB1s0, 0);

    {   // peeled tile 11 (parity 1, uses bB1s0; no staging)
        const char* Ab = smem + 32768;
        const char* Bb = smem + 65536 + 32768;
        /* ph0 */
        READ_BSEG1(Bb);
        READ_AQ(aS1, Ab, 1);
        MFMA_Q(0, aS0, bB1s0);
        /* ph1 */
        VMW(0); BAR();
        READ_AQ(aS0, Ab, 2);
        MFMA_Q(1, aS1, bB1s0);
        /* ph2 */
        READ_AQ(aS1, Ab, 3);
        MFMA_Q(2, aS0, bB1s0);
        /* ph3 */
        MFMA_Q(3, aS1, bB1s0);
    }

    // ---------------- epilogue: t-Student + row sums ----------------
    // C/D map: row = wr*128 + m*16 + (l>>4)*4 + j (A-side), col = wc*64 + n*16 + (l&15) (B-side)
    float* red = (float*)smem;  // 256 rows x 4 wc
    __syncthreads();            // all LDS reads of the K-loop done before reuse as 'red'
    #pragma unroll
    for (int m = 0; m < 8; ++m) {
        #pragma unroll
        for (int j = 0; j < 4; ++j) {
            float s = 0.f;
            #pragma unroll
            for (int n = 0; n < 4; ++n) s += tstudent(acc[m][n][j]);
            s += __shfl_xor(s, 1);
            s += __shfl_xor(s, 2);
            s += __shfl_xor(s, 4);
            s += __shfl_xor(s, 8);
            if ((l & 15) == 0) {
                int row = wr * 128 + m * 16 + (l >> 4) * 4 + j;
                red[row * 4 + wc] = s;
            }
        }
    }
    __syncthreads();
    if (t < BM) {
        partial[(size_t)bc * N_ROWS + rowbase + t] = red[t * 4 + 0] + red[t * 4 + 1] + red[t * 4 + 2] + red[t * 4 + 3];
    }
}

// ---------------- kernel 3: per-row denom + ratio, per-block sums ----------------
__global__ __launch_bounds__(256) void reduce_kernel(const float* __restrict__ partial,
                                                     const float* __restrict__ num,
                                                     float* __restrict__ blocksum) {
    int row = blockIdx.x * 256 + threadIdx.x;
    float d = 0.f;
    #pragma unroll 8
    for (int ct = 0; ct < NT2; ++ct) d += partial[(size_t)ct * N_ROWS + row];
    float s = num[row] / d;
    for (int off = 32; off; off >>= 1) s += __shfl_down(s, off);
    __shared__ float wsum[4];
    if ((threadIdx.x & 63) == 0) wsum[threadIdx.x >> 6] = s;
    __syncthreads();
    if (threadIdx.x == 0) blocksum[blockIdx.x] = wsum[0] + wsum[1] + wsum[2] + wsum[3];
}

// ---------------- kernel 4: final scalar ----------------
__global__ __launch_bounds__(64) void final_kernel(const float* __restrict__ blocksum,
                                                   float* __restrict__ out) {
    int l = threadIdx.x;
    float s = (l < 32) ? blocksum[l] : 0.f;
    for (int off = 32; off; off >>= 1) s += __shfl_down(s, off);
    if (l == 0) out[0] = -(s / (float)N_ROWS);
}

extern "C" void kernel_launch(void* const* d_in, const int* in_sizes, int n_in,
                              void* d_out, int out_size, void* d_ws, size_t ws_size,
                              hipStream_t stream) {
    const float* z1 = (const float*)d_in[0];
    const float* z2 = (const float*)d_in[1];
    char* ws = (char*)d_ws;
    const size_t n_bytes = (size_t)N_ROWS * DIM * 2;  // 12,582,912
    unsigned short* n1 = (unsigned short*)ws;
    unsigned short* n2 = (unsigned short*)(ws + n_bytes);
    float* num      = (float*)(ws + 2 * n_bytes);                         // 32 KB
    float* partial  = (float*)(ws + 2 * n_bytes + 32768);                 // 1 MB used
    float* blocksum = (float*)(ws + 2 * n_bytes + 32768 + 2097152);       // 128 B

    hipFuncSetAttribute((const void*)gemm_kernel,
                        hipFuncAttributeMaxDynamicSharedMemorySize, LDS_BYTES);

    norm_kernel<<<N_ROWS, 256, 0, stream>>>(z1, z2, n1, n2, num);
    gemm_kernel<<<NT2 * NT2, 512, LDS_BYTES, stream>>>(n1, n2, partial);
    reduce_kernel<<<N_ROWS / 256, 256, 0, stream>>>(partial, num, blocksum);
    final_kernel<<<1, 64, 0, stream>>>(blocksum, (float*)d_out);
}